// Round 3
// baseline (608.881 us; speedup 1.0000x reference)
//
#include <hip/hip_runtime.h>

// Correlation-1D: out[b,d,h,w] = sum_c x1[b,c,h,w] * x2pad[b,c,h,w+d], d in [0,41)
// x2pad = x2 zero-padded by 20 on each side of W.
// Shapes: x1,x2 [8,256,96,320] fp32 -> out [8,41,96,320] fp32.
//
// Memory-bound op (543 MB compulsory / 6.3 TB/s ~= 86 us). Design:
//  - 1 block per (b,h) row: grid 768, block 320 threads (80 w-groups x 4 d-groups)
//  - per-thread 4(w) x 12(d) register tile: 48 acc VGPRs, window start 4tw+12td
//    is 16B-aligned -> x2 window read as 4x ds_read_b128 (64 B per 48 FMAs)
//  - x2 row staged in LDS, zero-padded to 368 floats (free boundary handling,
//    free masking of the d=41..47 tail), double-buffered, ONE barrier per
//    8-channel chunk (stores go to the opposite buffer)
//  - x1 read straight from global as coalesced float4 (d-groups hit L1)

#define C_    256
#define H_    96
#define W_    320
#define D_    41
#define CC_   8
#define NCH_  (C_ / CC_)      // 32 chunks
#define WG_   80              // w-groups (WT=4)
#define DG_   4               // d-groups (DT=12, covers 48, tail masked)
#define NTHR_ (WG_ * DG_)     // 320 threads
#define LROW_ 368             // 20 zero | 320 data | 28 zero  (16B-aligned rows)
#define CHW_  (H_ * W_)       // 30720

__global__ __launch_bounds__(NTHR_) void corr1d_kernel(
    const float* __restrict__ x1, const float* __restrict__ x2,
    float* __restrict__ out)
{
    __shared__ float sx2[2][CC_][LROW_];

    const int t  = threadIdx.x;
    const int tw = t % WG_;         // 0..79
    const int td = t / WG_;         // 0..3
    const int b  = blockIdx.x / H_;
    const int h  = blockIdx.x % H_;

    // Zero the pad regions of both buffers once (they are never overwritten).
    for (int i = t; i < 2 * CC_ * 48; i += NTHR_) {
        int buf = i / (CC_ * 48);
        int rem = i - buf * (CC_ * 48);
        int row = rem / 48;
        int p   = rem - row * 48;
        int idx = (p < 20) ? p : (320 + p);   // p=20..47 -> 340..367
        sx2[buf][row][idx] = 0.0f;
    }

    const int base = b * C_ * CHW_ + h * W_;  // + c*CHW_ + w
    const int w4   = 4 * tw;
    const int s4   = w4 + 12 * td;            // window start (16B aligned)

    // Stage chunk 0 into buffer 0: thread stages rows td and td+4, col 4*tw.
    float4 st0 = *(const float4*)(x2 + base + td * CHW_ + w4);
    float4 st1 = *(const float4*)(x2 + base + (td + 4) * CHW_ + w4);
    *(float4*)(&sx2[0][td][20 + w4])     = st0;
    *(float4*)(&sx2[0][td + 4][20 + w4]) = st1;

    float acc[12][4];
#pragma unroll
    for (int dd = 0; dd < 12; ++dd)
#pragma unroll
        for (int i = 0; i < 4; ++i) acc[dd][i] = 0.0f;

    for (int k = 0; k < NCH_; ++k) {
        __syncthreads();   // protects: prev writes -> this chunk's reads, and
                           // this chunk's writes (other buf) vs prev reads of it
        const int  cur  = k & 1;
        const bool more = (k + 1 < NCH_);
        if (more) {
            const int c0n = (k + 1) * CC_;
            st0 = *(const float4*)(x2 + base + (c0n + td) * CHW_ + w4);
            st1 = *(const float4*)(x2 + base + (c0n + td + 4) * CHW_ + w4);
        }

        const float* __restrict__ bp = &sx2[cur][0][0];
        const int c0 = k * CC_;
#pragma unroll
        for (int cc = 0; cc < CC_; ++cc) {
            float4 a = *(const float4*)(x1 + base + (c0 + cc) * CHW_ + w4);
            const float* r = bp + cc * LROW_ + s4;
            float4 q0 = *(const float4*)(r);
            float4 q1 = *(const float4*)(r + 4);
            float4 q2 = *(const float4*)(r + 8);
            float4 q3 = *(const float4*)(r + 12);
            float win[16] = {q0.x, q0.y, q0.z, q0.w, q1.x, q1.y, q1.z, q1.w,
                             q2.x, q2.y, q2.z, q2.w, q3.x, q3.y, q3.z, q3.w};
            float av[4] = {a.x, a.y, a.z, a.w};
#pragma unroll
            for (int dd = 0; dd < 12; ++dd)
#pragma unroll
                for (int i = 0; i < 4; ++i)
                    acc[dd][i] = fmaf(av[i], win[dd + i], acc[dd][i]);
        }

        if (more) {
            *(float4*)(&sx2[cur ^ 1][td][20 + w4])     = st0;
            *(float4*)(&sx2[cur ^ 1][td + 4][20 + w4]) = st1;
        }
    }

    // Store: d = 12*td + dd, skip the masked d >= 41 tail.
    const int ob = b * (D_ * CHW_) + h * W_ + w4;
#pragma unroll
    for (int dd = 0; dd < 12; ++dd) {
        const int d = 12 * td + dd;
        if (d < D_) {
            float4 o;
            o.x = acc[dd][0]; o.y = acc[dd][1];
            o.z = acc[dd][2]; o.w = acc[dd][3];
            *(float4*)(out + ob + d * CHW_) = o;
        }
    }
}

extern "C" void kernel_launch(void* const* d_in, const int* in_sizes, int n_in,
                              void* d_out, int out_size, void* d_ws, size_t ws_size,
                              hipStream_t stream)
{
    const float* x1 = (const float*)d_in[0];
    const float* x2 = (const float*)d_in[1];
    float* out      = (float*)d_out;
    const int B     = in_sizes[0] / (C_ * CHW_);   // 8
    corr1d_kernel<<<dim3(B * H_), dim3(NTHR_), 0, stream>>>(x1, x2, out);
}